// Round 3
// baseline (670.188 us; speedup 1.0000x reference)
//
#include <hip/hip_runtime.h>
#include <cstdint>
#include <cstddef>

#define BB 96
#define SS 4
#define TT 16
#define KK 36
#define VDIM 1024
#define QDIM 512
#define HH 512
#define NROWS 3264
#define MM (NROWS * KK)   // 117504

typedef __attribute__((ext_vector_type(8))) short short8;
typedef __attribute__((ext_vector_type(4))) float f32x4;

static __device__ __forceinline__ unsigned short f2bf(float f) {
    union { float f; unsigned u; } v; v.f = f;
    unsigned u = v.u;
    u += 0x7FFFu + ((u >> 16) & 1u);   // RNE
    return (unsigned short)(u >> 16);
}

__device__ __forceinline__ void gload_lds16(const void* g, void* l) {
    __builtin_amdgcn_global_load_lds(
        (const __attribute__((address_space(1))) unsigned int*)g,
        (__attribute__((address_space(3))) unsigned int*)l, 16, 0, 0);
}

#define SB() __builtin_amdgcn_sched_barrier(0)

// ---------------------------------------------------------------------------
// Kernel 0: W1v (rows 0..1023 of w1) -> bf16 transposed w1vT[c][k]
// ---------------------------------------------------------------------------
__global__ __launch_bounds__(256) void prep_w1T(const float* __restrict__ w1,
                                                unsigned short* __restrict__ w1vT) {
    int idx = blockIdx.x * 256 + threadIdx.x;
    int k = idx & 1023;
    int c = idx >> 10;
    w1vT[idx] = f2bf(w1[(size_t)k * HH + c]);
}

// ---------------------------------------------------------------------------
// Kernel 1: per-(b,s) segment starts/lengths via LDS scan (one block)
// ---------------------------------------------------------------------------
__global__ __launch_bounds__(512) void starts_kernel(const int* __restrict__ tags,
                                                     int* __restrict__ starts,
                                                     int* __restrict__ lengths) {
    __shared__ int sl[BB * SS];
    int tid = threadIdx.x;
    int len = 0;
    if (tid < BB * SS) {
#pragma unroll
        for (int i = 0; i < TT; ++i) len += tags[tid * TT + i];
        sl[tid] = len;
    }
    __syncthreads();
    for (int off = 1; off < BB * SS; off <<= 1) {
        int v = 0;
        if (tid < BB * SS && tid >= off) v = sl[tid - off];
        __syncthreads();
        if (tid < BB * SS) sl[tid] += v;
        __syncthreads();
    }
    if (tid < BB * SS) { starts[tid] = sl[tid] - len; lengths[tid] = len; }
}

// ---------------------------------------------------------------------------
// Kernel 2: qp[n][h] = b1[h] + sum_d q[n][d] * w1[1024+d][h]  (fp32 exact)
// 8 rows / block, grid = NROWS/8 = 408, d-unroll 8 for ILP
// ---------------------------------------------------------------------------
__global__ __launch_bounds__(256) void qproj_kernel(const float* __restrict__ q,
                                                    const float* __restrict__ w1,
                                                    const float* __restrict__ b1,
                                                    float* __restrict__ qp) {
    __shared__ float qs[8 * QDIM];   // 16 KB
    int tid = threadIdx.x;
    int n0 = blockIdx.x * 8;
    const float4* src = (const float4*)(q + (size_t)n0 * QDIM);
    float4* dst = (float4*)qs;
    for (int i = tid; i < 8 * QDIM / 4; i += 256) dst[i] = src[i];
    __syncthreads();

    int cg = tid & 127;
    int h  = cg * 4;
    int rh = tid >> 7;       // 0..1
    int r0 = rh * 4;

    float4 acc[4];
    float4 bv = *(const float4*)(b1 + h);
#pragma unroll
    for (int r = 0; r < 4; ++r) acc[r] = bv;

    for (int d = 0; d < QDIM; d += 8) {
        float4 w[8];
#pragma unroll
        for (int j = 0; j < 8; ++j)
            w[j] = *(const float4*)(w1 + (size_t)(VDIM + d + j) * HH + h);
#pragma unroll
        for (int r = 0; r < 4; ++r) {
            float4 q0 = *(const float4*)&qs[(r0 + r) * QDIM + d];
            float4 q1 = *(const float4*)&qs[(r0 + r) * QDIM + d + 4];
            acc[r].x += q0.x*w[0].x + q0.y*w[1].x + q0.z*w[2].x + q0.w*w[3].x
                      + q1.x*w[4].x + q1.y*w[5].x + q1.z*w[6].x + q1.w*w[7].x;
            acc[r].y += q0.x*w[0].y + q0.y*w[1].y + q0.z*w[2].y + q0.w*w[3].y
                      + q1.x*w[4].y + q1.y*w[5].y + q1.z*w[6].y + q1.w*w[7].y;
            acc[r].z += q0.x*w[0].z + q0.y*w[1].z + q0.z*w[2].z + q0.w*w[3].z
                      + q1.x*w[4].z + q1.y*w[5].z + q1.z*w[6].z + q1.w*w[7].z;
            acc[r].w += q0.x*w[0].w + q0.y*w[1].w + q0.z*w[2].w + q0.w*w[3].w
                      + q1.x*w[4].w + q1.y*w[5].w + q1.z*w[6].w + q1.w*w[7].w;
        }
    }
#pragma unroll
    for (int r = 0; r < 4; ++r)
        *(float4*)(qp + (size_t)(n0 + r0 + r) * HH + h) = acc[r];
}

// ---------------------------------------------------------------------------
// Kernel 3: main GEMM. BM=64, BN=512 (full H), BK=32. 256 threads = 4 waves
// (1M x 4N), wave tile 64x128. A: direct global->reg->bf16, depth-2 prefetch,
// no LDS. B: global_load_lds double-buffered, XOR-swizzled, counted vmcnt,
// raw s_barrier. Epilogue: relu(acc + qp) . w2 -> logits.
// ---------------------------------------------------------------------------
__global__ __launch_bounds__(256, 2) void main_gemm(const float* __restrict__ v,
                                                    const unsigned short* __restrict__ w1vT,
                                                    const float* __restrict__ qp,
                                                    const float* __restrict__ w2,
                                                    float* __restrict__ logits) {
    __shared__ __align__(16) unsigned short Bt[2][512][32];   // 64 KB
    __shared__ float fl[4][64];

    int tid  = threadIdx.x;
    int lane = tid & 63;
    int wid  = tid >> 6;      // 0..3 = wn
    int m0   = blockIdx.x * 64;
    int lr   = lane & 15;
    int lg   = lane >> 4;

    // --- B staging addressing (fixed per thread): 8 chunks of 16 cols/wave ---
    const unsigned short* bsrc[8];
#pragma unroll
    for (int i = 0; i < 8; ++i) {
        int cc = (wid * 8 + i) * 16 + (lane >> 2);
        int gg = (lane & 3) ^ ((cc ^ (cc >> 2)) & 3);
        bsrc[i] = w1vT + (size_t)cc * VDIM + gg * 8;
    }
    unsigned short* bdst_0 = &Bt[0][wid * 128][0];   // + i*512 per chunk
    unsigned short* bdst_1 = &Bt[1][wid * 128][0];

    // --- B read offsets (bytes, fixed per thread) ---
    int lofs[8];
#pragma unroll
    for (int nt = 0; nt < 8; ++nt) {
        int col = wid * 128 + nt * 16 + lr;
        lofs[nt] = col * 64 + ((lg ^ ((col ^ (col >> 2)) & 3)) * 16);
    }
    const char* bbase_0 = (const char*)&Bt[0][0][0];
    const char* bbase_1 = (const char*)&Bt[1][0][0];

    // --- A addressing: lane holds rows (mt*16+lr), k = lg*8..+7 ---
    const float* a_ptr = v + (size_t)(m0 + lr) * VDIM + lg * 8;

    f32x4 acc[4][8];
#pragma unroll
    for (int mt = 0; mt < 4; ++mt)
#pragma unroll
        for (int nt = 0; nt < 8; ++nt) acc[mt][nt] = (f32x4){0.f, 0.f, 0.f, 0.f};

    float4 ar0[8], ar1[8];
    short8 af0[4], af1[4];

#define LOAD_A(AR, KA)                                                        \
    _Pragma("unroll") for (int m = 0; m < 4; ++m) {                           \
        AR[2 * m]     = *(const float4*)(a_ptr + m * 16 * VDIM + (KA));       \
        AR[2 * m + 1] = *(const float4*)(a_ptr + m * 16 * VDIM + (KA) + 4);   \
    }

#define CONV_A(AF, AR)                                                        \
    _Pragma("unroll") for (int m = 0; m < 4; ++m) {                           \
        unsigned short tc[8] = {f2bf(AR[2*m].x),   f2bf(AR[2*m].y),           \
                                f2bf(AR[2*m].z),   f2bf(AR[2*m].w),           \
                                f2bf(AR[2*m+1].x), f2bf(AR[2*m+1].y),         \
                                f2bf(AR[2*m+1].z), f2bf(AR[2*m+1].w)};        \
        AF[m] = *(const short8*)tc;                                           \
    }

    // ---- prologue: B(0)->buf0; A(0)->ar0; A(1)->ar1; convert af0 ----
#pragma unroll
    for (int i = 0; i < 8; ++i) gload_lds16(bsrc[i], bdst_0 + i * 512);
    SB();
    LOAD_A(ar0, 0)
    SB();
    LOAD_A(ar1, 32)
    SB();
    asm volatile("s_waitcnt vmcnt(8)" ::: "memory");   // B(0), A(0) done
    SB();
    CONV_A(af0, ar0)

#define GEMM_BODY(T, ARI, ARC, AFU, AFC, CUR, NXT)                            \
  do {                                                                        \
    const int kB = ((T) < 31) ? ((T) + 1) * 32 : 992;                         \
    const int kA = ((T) < 30) ? ((T) + 2) * 32 : 992;                         \
    _Pragma("unroll") for (int i = 0; i < 8; ++i)                             \
        gload_lds16(bsrc[i] + kB, bdst_##NXT + i * 512);                      \
    SB();                                                                     \
    LOAD_A(ARI, kA)                                                           \
    SB();                                                                     \
    asm volatile("s_waitcnt vmcnt(24)" ::: "memory");  /* B(T) done */        \
    __builtin_amdgcn_s_barrier();                                             \
    SB();                                                                     \
    short8 bf[8];                                                             \
    _Pragma("unroll") for (int nt = 0; nt < 8; ++nt)                          \
        bf[nt] = *(const short8*)(bbase_##CUR + lofs[nt]);                    \
    __builtin_amdgcn_s_setprio(1);                                            \
    _Pragma("unroll") for (int mt = 0; mt < 4; ++mt)                          \
        _Pragma("unroll") for (int nt = 0; nt < 8; ++nt)                      \
            acc[mt][nt] = __builtin_amdgcn_mfma_f32_16x16x32_bf16(            \
                AFU[mt], bf[nt], acc[mt][nt], 0, 0, 0);                       \
    __builtin_amdgcn_s_setprio(0);                                            \
    SB();                                                                     \
    asm volatile("s_waitcnt vmcnt(16)" ::: "memory");  /* A(T+1) done */      \
    SB();                                                                     \
    CONV_A(AFC, ARC)                                                          \
    __builtin_amdgcn_s_barrier();                                             \
    SB();                                                                     \
  } while (0)

    for (int it = 0; it < 32; it += 2) {
        GEMM_BODY(it,     ar0, ar1, af0, af1, 0, 1);
        GEMM_BODY(it + 1, ar1, ar0, af1, af0, 1, 0);
    }
#undef GEMM_BODY
#undef LOAD_A
#undef CONV_A

    __syncthreads();   // full drain before epilogue (also drains dummy loads)

    // ---- epilogue: relu(acc + qp) . w2 -> logits (b2 cancels in softmax) ----
    float part[4][4] = {{0.f}};
#pragma unroll
    for (int nt = 0; nt < 8; ++nt) {
        int c = wid * 128 + nt * 16 + lr;
        float w2v = w2[c];
#pragma unroll
        for (int mt = 0; mt < 4; ++mt)
#pragma unroll
            for (int r = 0; r < 4; ++r) {
                int row = mt * 16 + lg * 4 + r;
                int n = (m0 + row) / KK;
                float pre = acc[mt][nt][r] + qp[(size_t)n * HH + c];
                part[mt][r] += fmaxf(pre, 0.f) * w2v;
            }
    }
#pragma unroll
    for (int mt = 0; mt < 4; ++mt)
#pragma unroll
        for (int r = 0; r < 4; ++r) {
            float s = part[mt][r];
            s += __shfl_xor(s, 1, 64);
            s += __shfl_xor(s, 2, 64);
            s += __shfl_xor(s, 4, 64);
            s += __shfl_xor(s, 8, 64);
            if (lr == 0) fl[wid][mt * 16 + lg * 4 + r] = s;
        }
    __syncthreads();
    if (tid < 64) logits[m0 + tid] = fl[0][tid] + fl[1][tid] + fl[2][tid] + fl[3][tid];
}

// ---------------------------------------------------------------------------
// Kernel 4: masked softmax. One wave per (b,s,t).
// ---------------------------------------------------------------------------
__global__ __launch_bounds__(256) void softmax_kernel(const float* __restrict__ logits,
                                                      const float* __restrict__ box_mask,
                                                      const int* __restrict__ starts,
                                                      const int* __restrict__ lengths,
                                                      float* __restrict__ out) {
    int lane = threadIdx.x & 63;
    int g = blockIdx.x * 4 + (threadIdx.x >> 6);   // 0 .. B*S*T-1
    int t   = g & (TT - 1);
    int row = g >> 4;
    int b   = row >> 2;

    int length = lengths[row];
    int start  = starts[row];

    int k = lane;
    bool kv = k < KK;
    float mval = kv ? box_mask[b * KK + k] : 0.f;
    bool act = kv && (mval != 0.f);

    float l = 0.f;
    if (act && t < length) l = logits[(size_t)(start + t) * KK + k];

    float lm = act ? l : -1e30f;
#pragma unroll
    for (int off = 32; off >= 1; off >>= 1) lm = fmaxf(lm, __shfl_xor(lm, off, 64));

    float e = act ? expf(l - lm) : 0.f;
    float se = e;
#pragma unroll
    for (int off = 32; off >= 1; off >>= 1) se += __shfl_xor(se, off, 64);

    if (kv) out[(size_t)g * KK + k] = e / se;
}

// ---------------------------------------------------------------------------
extern "C" void kernel_launch(void* const* d_in, const int* in_sizes, int n_in,
                              void* d_out, int out_size, void* d_ws, size_t ws_size,
                              hipStream_t stream) {
    const float* v        = (const float*)d_in[0];
    const float* q        = (const float*)d_in[1];
    const float* box_mask = (const float*)d_in[2];
    const int*   tags     = (const int*)d_in[3];
    const float* w1       = (const float*)d_in[4];
    const float* b1       = (const float*)d_in[5];
    const float* w2       = (const float*)d_in[6];

    unsigned short* w1vT  = (unsigned short*)d_ws;                         // 1 MB
    float* qp      = (float*)((char*)d_ws + 1048576);                      // 6.68 MB
    float* logits  = (float*)((char*)d_ws + 1048576 + 6684672);            // 470 KB
    int*   starts  = (int*)((char*)d_ws + 1048576 + 6684672 + 470016);
    int*   lengths = (int*)((char*)d_ws + 1048576 + 6684672 + 470016 + 1536);
    float* out     = (float*)d_out;

    hipLaunchKernelGGL(prep_w1T, dim3((HH * VDIM) / 256), dim3(256), 0, stream, w1, w1vT);
    hipLaunchKernelGGL(starts_kernel, dim3(1), dim3(512), 0, stream, tags, starts, lengths);
    hipLaunchKernelGGL(qproj_kernel, dim3(NROWS / 8), dim3(256), 0, stream, q, w1, b1, qp);
    hipLaunchKernelGGL(main_gemm, dim3(MM / 64), dim3(256), 0, stream,
                       v, w1vT, qp, w2, logits);
    hipLaunchKernelGGL(softmax_kernel, dim3((BB * SS * TT) / 4), dim3(256), 0, stream,
                       logits, box_mask, starts, lengths, out);
}